// Round 11
// baseline (217.408 us; speedup 1.0000x reference)
//
#include <hip/hip_runtime.h>
#include <hip/hip_bf16.h>

#define NROW 8192
#define FINC 256
#define FOUTC 256
#define BM 64
#define BK 32
#define KSPLIT 8
#define KLOC (NROW / KSPLIT)   // 1024
#define NTL (KLOC / BK)        // 32 K-steps per block

typedef __attribute__((ext_vector_type(8))) short bf16x8;
typedef __attribute__((ext_vector_type(4))) float f32x4;

__device__ __forceinline__ unsigned short f2bf(float f) {
  unsigned u = __float_as_uint(f);
  u += 0x7fffu + ((u >> 16) & 1u);   // round-to-nearest-even
  return (unsigned short)(u >> 16);
}
__device__ __forceinline__ float bf2f(unsigned short h) {
  return __uint_as_float(((unsigned)h) << 16);
}

// ---- kernel 1: D[i] = 1/sqrt(1 + sum_j adj[i][j]); one wave per row ----
__global__ __launch_bounds__(256) void rowsum_kernel(const float* __restrict__ adj,
                                                     float* __restrict__ D) {
  const int row = blockIdx.x * 4 + (threadIdx.x >> 6);
  const int l = threadIdx.x & 63;
  const float4* p = reinterpret_cast<const float4*>(adj + (size_t)row * NROW);
  float s0 = 0.f, s1 = 0.f, s2 = 0.f, s3 = 0.f;
#pragma unroll
  for (int i = 0; i < 8; ++i) {
    float4 a = p[l + (i * 4 + 0) * 64];
    float4 b = p[l + (i * 4 + 1) * 64];
    float4 c = p[l + (i * 4 + 2) * 64];
    float4 d = p[l + (i * 4 + 3) * 64];
    s0 += (a.x + a.y) + (a.z + a.w);
    s1 += (b.x + b.y) + (b.z + b.w);
    s2 += (c.x + c.y) + (c.z + c.w);
    s3 += (d.x + d.y) + (d.z + d.w);
  }
  float s = (s0 + s1) + (s2 + s3);
#pragma unroll
  for (int off = 32; off > 0; off >>= 1) s += __shfl_down(s, off, 64);
  if (l == 0) D[row] = 1.0f / sqrtf(s + 1.0f);
}

// ---- kernel 2: s2T[f][j] = s2R[j][f] = bf16( D[j] * (x @ W)[j][f] ) ----
__global__ __launch_bounds__(256) void support_kernel(const float* __restrict__ x,
                                                      const float* __restrict__ W,
                                                      const float* __restrict__ D,
                                                      unsigned short* __restrict__ s2T,
                                                      unsigned short* __restrict__ s2R) {
  __shared__ float xs[32][FINC];
  const int t = threadIdx.x;
  const int r0 = blockIdx.x * 32;
  {
    const float4* xg = reinterpret_cast<const float4*>(x + (size_t)r0 * FINC);
    float4* xl = reinterpret_cast<float4*>(&xs[0][0]);
#pragma unroll
    for (int i = 0; i < 8; ++i) xl[t + i * 256] = xg[t + i * 256];
  }
  __syncthreads();
  const int w = t >> 6, l = t & 63;
  float acc[8][4] = {};
  const float4* W4 = reinterpret_cast<const float4*>(W);
#pragma unroll 4
  for (int k = 0; k < FINC; ++k) {
    float4 wv = W4[k * 64 + l];
#pragma unroll
    for (int m = 0; m < 8; ++m) {
      float xv = xs[w * 8 + m][k];
      acc[m][0] = fmaf(xv, wv.x, acc[m][0]);
      acc[m][1] = fmaf(xv, wv.y, acc[m][1]);
      acc[m][2] = fmaf(xv, wv.z, acc[m][2]);
      acc[m][3] = fmaf(xv, wv.w, acc[m][3]);
    }
  }
#pragma unroll
  for (int m = 0; m < 8; ++m) {
    const int j = r0 + w * 8 + m;
    const float d = D[j];
    const int f0 = l * 4;
    ushort4 rv;
    rv.x = f2bf(d * acc[m][0]);
    rv.y = f2bf(d * acc[m][1]);
    rv.z = f2bf(d * acc[m][2]);
    rv.w = f2bf(d * acc[m][3]);
    *reinterpret_cast<ushort4*>(&s2R[(size_t)j * FOUTC + f0]) = rv;
    s2T[(size_t)(f0 + 0) * NROW + j] = rv.x;
    s2T[(size_t)(f0 + 1) * NROW + j] = rv.y;
    s2T[(size_t)(f0 + 2) * NROW + j] = rv.z;
    s2T[(size_t)(f0 + 3) * NROW + j] = rv.w;
  }
}

// ---- kernel 3: K-split GEMM. BM=64 x BN=256 x BK=32, KSPLIT=8.
// LDS = 40 KB -> 4 blocks/CU; grid 1024 -> 4 resident (32 waves/CU).
// r8-proven counted-vmcnt schedule, recomputed for a {B x2, A x1} window:
// W1 = vmcnt(1) (B(t) landed, A(t+1) in flight), W2 = vmcnt(3) (A(t+1)
// landed). Never drains in the main loop; one barrier per K-step.
// bid%8 = ks -> each XCD's B working set = one 512 KB slice (L2-resident).
// Swizzle for 64-B rows: 16-B unit u stored at u ^ ((row>>1)&3) (2-way, free).
__global__ __launch_bounds__(512, 8) void gcn_gemm_kernel(const float* __restrict__ adj,
                                                          const unsigned short* __restrict__ s2T,
                                                          float* __restrict__ part) {
  __shared__ __align__(16) unsigned short As[2][BM * BK];      // 2 x 4 KB
  __shared__ __align__(16) unsigned short Bs[2][FOUTC * BK];   // 2 x 16 KB

  const int t = threadIdx.x, wid = t >> 6, l = t & 63;
  const int bid = blockIdx.x;
  const int m = bid >> 3, ks = bid & 7;      // bid%8 == XCD id == ks
  const int bm0 = m * BM;
  const size_t k0 = (size_t)ks * KLOC;

  // A staging: thread t -> row ar = t>>3, one float4 (16 B) at col (t&7)*4
  const int ar = t >> 3, ac = t & 7;
  const float4* arow = reinterpret_cast<const float4*>(adj + (size_t)(bm0 + ar) * NROW + k0) + ac;
  const unsigned awoff = (unsigned)(ar * 64 + (((ac >> 1) ^ ((ar >> 1) & 3)) << 4) + (ac & 1) * 8);

  // B staging via global_load_lds: chunk c = wid*2+i covers f-rows c*16..c*16+15;
  // lane l -> row l>>2, dest unit l&3; source unit pre-XOR (l&3)^((l>>3)&3) (G21)
  const unsigned bsrc = (unsigned)(((l & 3) ^ ((l >> 3) & 3)) * 16);
  const int brow = l >> 2;

  f32x4 acc[2][4] = {};

  const int wm = wid >> 2, wn = wid & 3;     // 2M x 4N wave grid (32 x 64 per wave)
  const int am0 = wm * 32, nb0 = wn * 64;
  const int fr = l & 15;
  const unsigned sw = (unsigned)((fr >> 1) & 3);
  const unsigned uq = (unsigned)(l >> 4);
  const unsigned aroff = (unsigned)((am0 + fr) * 64 + ((uq ^ sw) << 4));
  const unsigned broff = (unsigned)((nb0 + fr) * 64 + ((uq ^ sw) << 4));

  auto stageB = [&](int kt, int sl) {
#pragma unroll
    for (int i = 0; i < 2; ++i) {
      const int c = wid * 2 + i;
      const unsigned short* src =
          s2T + (size_t)(c * 16 + brow) * NROW + k0 + (size_t)kt * BK;
      __builtin_amdgcn_global_load_lds(
          (const __attribute__((address_space(1))) unsigned int*)((const char*)src + bsrc),
          (__attribute__((address_space(3))) unsigned int*)((char*)&Bs[sl][0] + c * 1024),
          16, 0, 0);
    }
  };
  auto writeA = [&](float4 v, int sl) {
    ushort4 u;
    u.x = f2bf(v.x); u.y = f2bf(v.y); u.z = f2bf(v.z); u.w = f2bf(v.w);
    *reinterpret_cast<ushort4*>((char*)&As[sl][0] + awoff) = u;
  };
  auto compute = [&](int sl) {
    const char* Ab = (const char*)&As[sl][0];
    const char* Bb = (const char*)&Bs[sl][0];
    bf16x8 a0 = *reinterpret_cast<const bf16x8*>(Ab + aroff);
    bf16x8 a1 = *reinterpret_cast<const bf16x8*>(Ab + aroff + 1024);
#pragma unroll
    for (int n = 0; n < 4; ++n) {
      bf16x8 b = *reinterpret_cast<const bf16x8*>(Bb + broff + n * 1024);
      acc[0][n] = __builtin_amdgcn_mfma_f32_16x16x32_bf16(a0, b, acc[0][n], 0, 0, 0);
      acc[1][n] = __builtin_amdgcn_mfma_f32_16x16x32_bf16(a1, b, acc[1][n], 0, 0, 0);
    }
  };

  // ---- prologue: A(0) | drain | writeA(0); B(0)x2; A(1) -> queue [B0,B0,A1] ----
  float4 aPa, aPb;
  {
    float4 v0 = arow[0];
    asm volatile("s_waitcnt vmcnt(0)" ::: "memory");
    writeA(v0, 0);
    stageB(0, 0);
    asm volatile("" ::: "memory");
    aPa = arow[8];   // A(1); step stride = 32 fp32 = 8 float4
  }

  // ---- main loop ----
#define GITER(T, SC, SN, AW, AN)                                               \
  asm volatile("s_waitcnt vmcnt(1) lgkmcnt(0)\n\ts_barrier" ::: "memory");     \
  stageB((T) + 1, SN);                                                         \
  asm volatile("" ::: "memory");                                               \
  AN = arow[((T) + 2) * 8];                                                    \
  compute(SC);                                                                 \
  asm volatile("s_waitcnt vmcnt(3)" ::: "memory");                             \
  writeA(AW, SN);

#pragma unroll 1
  for (int tt = 0; tt < NTL - 2; tt += 2) {
    GITER(tt + 0, 0, 1, aPa, aPb)
    GITER(tt + 1, 1, 0, aPb, aPa)
  }
#undef GITER
  // t = NTL-2 (slot 0): stage B(NTL-1); no A prefetch; A(NTL-1) = aPa
  asm volatile("s_waitcnt vmcnt(1) lgkmcnt(0)\n\ts_barrier" ::: "memory");
  stageB(NTL - 1, 1);
  compute(0);
  asm volatile("s_waitcnt vmcnt(2)" ::: "memory");   // A(NTL-1) landed
  writeA(aPa, 1);
  // t = NTL-1 (slot 1): drain
  asm volatile("s_waitcnt vmcnt(0) lgkmcnt(0)\n\ts_barrier" ::: "memory");
  compute(1);

  // ---- epilogue: f32 partials; C/D layout col = l&15, row = (l>>4)*4 + q ----
  float* pout = part + (size_t)ks * NROW * FOUTC;
#pragma unroll
  for (int mm = 0; mm < 2; ++mm) {
#pragma unroll
    for (int n = 0; n < 4; ++n) {
#pragma unroll
      for (int q = 0; q < 4; ++q) {
        const int i = bm0 + am0 + mm * 16 + (l >> 4) * 4 + q;
        const int f = nb0 + n * 16 + fr;
        pout[(size_t)i * FOUTC + f] = acc[mm][n][q];
      }
    }
  }
}

// ---- kernel 4: out[i][f] = relu( (sum_ks part + s2R[i][f]) * D[i] + b[f] ) ----
__global__ __launch_bounds__(256) void combine_kernel(const float* __restrict__ part,
                                                      const unsigned short* __restrict__ s2R,
                                                      const float* __restrict__ D,
                                                      const float* __restrict__ bias,
                                                      float* __restrict__ out) {
  const int idx = blockIdx.x * 256 + threadIdx.x;   // one float4 per thread
  const int i = idx >> 6;
  const int f0 = (idx & 63) * 4;
  const size_t off = (size_t)i * FOUTC + f0;
  const size_t stride = (size_t)NROW * FOUTC;
  float4 s = *reinterpret_cast<const float4*>(part + off);
#pragma unroll
  for (int ks = 1; ks < KSPLIT; ++ks) {
    float4 p = *reinterpret_cast<const float4*>(part + (size_t)ks * stride + off);
    s.x += p.x; s.y += p.y; s.z += p.z; s.w += p.w;
  }
  ushort4 sv = *reinterpret_cast<const ushort4*>(s2R + off);
  float di = D[i];
  float4 bv = *reinterpret_cast<const float4*>(bias + f0);
  float4 o;
  o.x = fmaxf((s.x + bf2f(sv.x)) * di + bv.x, 0.f);
  o.y = fmaxf((s.y + bf2f(sv.y)) * di + bv.y, 0.f);
  o.z = fmaxf((s.z + bf2f(sv.z)) * di + bv.z, 0.f);
  o.w = fmaxf((s.w + bf2f(sv.w)) * di + bv.w, 0.f);
  *reinterpret_cast<float4*>(out + off) = o;
}

// ================= fallback path (round-3, used if ws too small) =============
__global__ __launch_bounds__(512) void gemm_fb(const float* __restrict__ adj,
                                               const unsigned short* __restrict__ s2T,
                                               const float* __restrict__ D,
                                               const float* __restrict__ bias,
                                               float* __restrict__ out) {
  __shared__ __align__(16) unsigned short Asf[3][32 * 64];
  __shared__ __align__(16) unsigned short Bsf[3][FOUTC * 64];
  const int t = threadIdx.x, wid = t >> 6, l = t & 63;
  const int bm0 = blockIdx.x * 32;
  const int ar = t >> 4;
  const unsigned awoff = (unsigned)(ar * 128 + (((t & 15) * 8) ^ ((ar & 7) << 4)));
  const float4* arow = reinterpret_cast<const float4*>(adj + (size_t)(bm0 + ar) * NROW) + (t & 15);
  const int bn = l >> 3;
  const unsigned bks = (unsigned)(((l & 7) * 16) ^ (bn << 4));
  f32x4 acc[2][2] = {};
  const unsigned swz = (unsigned)((l & 7) << 4);
  const int fr = l & 15;
  const unsigned kb = (unsigned)((l >> 4) * 16);
  const int nb = wid * 32;
  const int NTF = NROW / 64;
  auto stageB = [&](int kt, int sl) {
#pragma unroll
    for (int i = 0; i < 4; ++i) {
      const int c = wid * 4 + i;
      const int n = c * 8 + bn;
      const unsigned short* src = s2T + (size_t)n * NROW + (size_t)kt * 64;
      __builtin_amdgcn_global_load_lds(
          (const __attribute__((address_space(1))) unsigned int*)((const char*)src + bks),
          (__attribute__((address_space(3))) unsigned int*)((char*)&Bsf[sl][0] + c * 1024),
          16, 0, 0);
    }
  };
  auto writeA = [&](float4 av, int sl) {
    ushort4 ab;
    ab.x = f2bf(av.x); ab.y = f2bf(av.y); ab.z = f2bf(av.z); ab.w = f2bf(av.w);
    *reinterpret_cast<ushort4*>((char*)&Asf[sl][0] + awoff) = ab;
  };
  auto compute = [&](int sl) {
    const char* Ab = (const char*)&Asf[sl][0];
    const char* Bb = (const char*)&Bsf[sl][0];
#pragma unroll
    for (int kk = 0; kk < 2; ++kk) {
      const unsigned kx = ((unsigned)(kk * 64) + kb) ^ swz;
      bf16x8 a0 = *reinterpret_cast<const bf16x8*>(Ab + fr * 128 + kx);
      bf16x8 a1 = *reinterpret_cast<const bf16x8*>(Ab + (fr + 16) * 128 + kx);
      bf16x8 b0 = *reinterpret_cast<const bf16x8*>(Bb + (nb + fr) * 128 + kx);
      bf16x8 b1 = *reinterpret_cast<const bf16x8*>(Bb + (nb + 16 + fr) * 128 + kx);
      acc[0][0] = __builtin_amdgcn_mfma_f32_16x16x32_bf16(a0, b0, acc[0][0], 0, 0, 0);
      acc[0][1] = __builtin_amdgcn_mfma_f32_16x16x32_bf16(a0, b1, acc[0][1], 0, 0, 0);
      acc[1][0] = __builtin_amdgcn_mfma_f32_16x16x32_bf16(a1, b0, acc[1][0], 0, 0, 0);
      acc[1][1] = __builtin_amdgcn_mfma_f32_16x16x32_bf16(a1, b1, acc[1][1], 0, 0, 0);
    }
  };
  float4 a0p, a1p, a2p;
  {
    float4 a0v = arow[0];
    asm volatile("" ::: "memory");
    stageB(0, 0);
    a1p = arow[16];
    asm volatile("" ::: "memory");
    stageB(1, 1);
    a2p = arow[32];
    asm volatile("s_waitcnt vmcnt(10)" ::: "memory");
    writeA(a0v, 0);
  }
#define PIPE_ITER(KT, S0, S1, S2, AW, AN)                                      \
  asm volatile("s_waitcnt vmcnt(5) lgkmcnt(0)\n\ts_barrier" ::: "memory");     \
  writeA(AW, S1);                                                              \
  stageB((KT) + 2, S2);                                                        \
  if ((KT) < NTF - 3) AN = arow[((KT) + 3) * 16];                              \
  compute(S0);
#pragma unroll 1
  for (int kt = 0; kt < NTF - 2; kt += 3) {
    PIPE_ITER(kt + 0, 0, 1, 2, a1p, a0p)
    PIPE_ITER(kt + 1, 1, 2, 0, a2p, a1p)
    PIPE_ITER(kt + 2, 2, 0, 1, a0p, a2p)
  }
#undef PIPE_ITER
  asm volatile("s_waitcnt vmcnt(4) lgkmcnt(0)\n\ts_barrier" ::: "memory");
  writeA(a1p, 1);
  compute(0);
  asm volatile("s_waitcnt vmcnt(0) lgkmcnt(0)\n\ts_barrier" ::: "memory");
  compute(1);
#pragma unroll
  for (int m = 0; m < 2; ++m) {
#pragma unroll
    for (int n = 0; n < 2; ++n) {
#pragma unroll
      for (int q = 0; q < 4; ++q) {
        const int i = bm0 + m * 16 + (l >> 4) * 4 + q;
        const int f = wid * 32 + n * 16 + fr;
        const float selfv = bf2f(s2T[(size_t)f * NROW + i]);
        float v = (acc[m][n][q] + selfv) * D[i] + bias[f];
        out[(size_t)i * FOUTC + f] = fmaxf(v, 0.0f);
      }
    }
  }
}

extern "C" void kernel_launch(void* const* d_in, const int* in_sizes, int n_in,
                              void* d_out, int out_size, void* d_ws, size_t ws_size,
                              hipStream_t stream) {
  const float* x   = (const float*)d_in[0];
  const float* adj = (const float*)d_in[1];
  const float* W   = (const float*)d_in[2];
  const float* b   = (const float*)d_in[3];
  float* out = (float*)d_out;

  char* wsb = (char*)d_ws;
  float* D            = (float*)wsb;                                   // 32 KB
  unsigned short* s2T = (unsigned short*)(wsb + 32768);                // 4 MB [f][j]
  unsigned short* s2R = (unsigned short*)(wsb + 32768 + (1u << 22));   // 4 MB [j][f]
  float* part         = (float*)(wsb + 32768 + (2u << 22));            // 64 MB

  const size_t need = 32768ull + (2ull << 22) + (size_t)KSPLIT * NROW * FOUTC * 4ull;
  rowsum_kernel<<<NROW / 4, 256, 0, stream>>>(adj, D);
  support_kernel<<<NROW / 32, 256, 0, stream>>>(x, W, D, s2T, s2R);
  if (ws_size >= need) {
    gcn_gemm_kernel<<<(NROW / BM) * KSPLIT, 512, 0, stream>>>(adj, s2T, part);
    combine_kernel<<<NROW * FOUTC / 1024, 256, 0, stream>>>(part, s2R, D, b, out);
  } else {
    gemm_fb<<<NROW / 32, 512, 0, stream>>>(adj, s2T, D, b, out);
  }
}